// Round 13
// baseline (210.215 us; speedup 1.0000x reference)
//
#include <hip/hip_runtime.h>

// GCN 2-layer. CSR via fixed-capacity bucketed counting sort, csr_pass fused with
// layer-1 MFMA GEMM (gemm blocks first, 2 tiles/block, W staged once), dinv folded
// into epilogues. Layer-2 COMMUTED (aggregate-then-GEMM) with mean-pool fused into
// GEMM2 epilogue (2 tiles/block persistent). fp8-e4m3 gather tables (x16).
// agg: 8-lane x uint4 row gathers (8 rows per wave instruction — halved gather
// instruction count vs 16-lane x uint2). 8 dispatches.

#define TPB 256
#define R_LOG 7
#define R_NODES 128          // nodes per bucket
#define NB_MAX 800           // >= ceil(100000/128)=782
#define CH 8192              // edges per bin_pass block
#define CAP_LOG 12
#define CAP 4096             // bucket capacity (avg fill ~2048 for E=1.6M, N=100K)

#define FS 16.0f             // fp8 table scale
#define FSI (1.0f / 16.0f)

typedef __attribute__((ext_vector_type(8))) short short8;
typedef __attribute__((ext_vector_type(4))) float f32x4;
typedef __attribute__((ext_vector_type(2))) float f32x2;

__device__ inline ushort f2bf(float x) {
    uint u = __float_as_uint(x);
    return (ushort)((u + 0x7FFFu + ((u >> 16) & 1u)) >> 16);   // RTNE
}

__device__ inline f32x2 shx2(f32x2 v, int m) {
    double d = __shfl_xor(__builtin_bit_cast(double, v), m);
    return __builtin_bit_cast(f32x2, d);
}

// ---------------- pass A: bin edges into fixed-cap 128-node buckets (packed) ----------
__global__ __launch_bounds__(1024) void bin_pass(const int* __restrict__ src,
                                                 const int* __restrict__ dst, int e,
                                                 int* __restrict__ gbcur,
                                                 int* __restrict__ buck, int nb) {
    __shared__ int vloc[CH];            // packed (src<<7)|(dst&127)
    __shared__ ushort bidl[CH];         // bucket id
    __shared__ int cnts[NB_MAX], starts[NB_MAX], cnts2[NB_MAX];
    int t = threadIdx.x;
    for (int i = t; i < nb; i += 1024) { cnts[i] = 0; cnts2[i] = 0; }
    __syncthreads();
    int base = blockIdx.x * CH;
    int lim = base + CH; if (lim > e) lim = e;
    int ce = lim - base;
    int nv = ce >> 2;
    const int4* s4 = (const int4*)(src + base);
    const int4* d4 = (const int4*)(dst + base);
    for (int i = t; i < nv; i += 1024) {
        int4 s = s4[i], d = d4[i];
        int j = i << 2;
#define BIN1(J, SS, DD)                                                      \
        { int b_ = (DD) >> R_LOG;                                            \
          vloc[J] = ((SS) << R_LOG) | ((DD) & (R_NODES - 1));                \
          bidl[J] = (ushort)b_;                                              \
          atomicAdd(&cnts[b_], 1); }
        BIN1(j,     s.x, d.x)
        BIN1(j + 1, s.y, d.y)
        BIN1(j + 2, s.z, d.z)
        BIN1(j + 3, s.w, d.w)
    }
    for (int j = (nv << 2) + t; j < ce; j += 1024) {
        int dv = dst[base + j], sv = src[base + j];
        BIN1(j, sv, dv)
    }
#undef BIN1
    __syncthreads();
    for (int i = t; i < nb; i += 1024) {
        int c = cnts[i];
        starts[i] = c ? ((i << CAP_LOG) + atomicAdd(&gbcur[i], c)) : 0;
    }
    __syncthreads();
    for (int j = t; j < ce; j += 1024) {
        int b = bidl[j];
        int pos = starts[b] + atomicAdd(&cnts2[b], 1);
        if (pos < ((b + 1) << CAP_LOG))                    // overflow clamp (never hit)
            buck[pos] = vloc[j];
    }
}

// ------- degree count per bucket (LDS histogram, int4 reads) + padded sum -------
__global__ __launch_bounds__(256) void count_pass(const int* __restrict__ buck,
                                                  const int* __restrict__ gbcur,
                                                  int* __restrict__ cnt,
                                                  float* __restrict__ dinv,
                                                  int* __restrict__ bktsum,
                                                  uint* __restrict__ t1z,
                                                  uint* __restrict__ t2z, int n) {
    __shared__ int c128[R_NODES];
    __shared__ int wred[4];
    int t = threadIdx.x;
    int b = blockIdx.x;
    if (b == 0 && t < 32) { t1z[t] = 0; t2z[t] = 0; }      // zero rows for pad slots
    if (t < R_NODES) c128[t] = 0;
    __syncthreads();
    int beg = b << CAP_LOG;
    int fill = gbcur[b]; if (fill > CAP) fill = CAP;
    int end = beg + fill;
    int nv = fill >> 2;
    const int4* b4 = (const int4*)(buck + beg);
    for (int i = t; i < nv; i += 256) {
        int4 v = b4[i];
        atomicAdd(&c128[v.x & (R_NODES - 1)], 1);
        atomicAdd(&c128[v.y & (R_NODES - 1)], 1);
        atomicAdd(&c128[v.z & (R_NODES - 1)], 1);
        atomicAdd(&c128[v.w & (R_NODES - 1)], 1);
    }
    for (int i = beg + (nv << 2) + t; i < end; i += 256)
        atomicAdd(&c128[buck[i] & (R_NODES - 1)], 1);
    __syncthreads();
    int node = (b << R_LOG) + t;
    int pv = 0;
    if (t < R_NODES && node < n) {
        int c = c128[t];
        cnt[node] = c;
        dinv[node] = rsqrtf((float)(c + 1));   // +1 self loop
        pv = (c + 7) & ~7;                      // padded degree
    }
    for (int o = 32; o; o >>= 1) pv += __shfl_down(pv, o);
    int lane = t & 63, wid = t >> 6;
    if (lane == 0) wred[wid] = pv;
    __syncthreads();
    if (t == 0) bktsum[b] = wred[0] + wred[1] + wred[2] + wred[3];
}

// ------ csr body (512-thread): self-scan base + intra-bucket prefix + scatter + pad ---
__device__ __forceinline__ void csr_body(int b, const int* __restrict__ buck,
                                         const int* __restrict__ cnt,
                                         const int* __restrict__ bktsum,
                                         const int* __restrict__ gbcur,
                                         int n, int nbkt, int* __restrict__ ew,
                                         int* __restrict__ rowptr) {
    __shared__ int rbase[R_NODES];
    __shared__ int cur[R_NODES];
    __shared__ int wtot[8], sred[8];
    int t = threadIdx.x;
    int n0 = b << R_LOG;
    int n1 = n0 + R_NODES; if (n1 > n) n1 = n;
    int nn = n1 - n0;
    int lane = t & 63, wid = t >> 6;
    // base = sum of bktsum[0..b)  (<=2 coalesced loads/thread, L2-hot)
    int s = 0;
    for (int i = t; i < b; i += 512) s += bktsum[i];
    for (int o = 32; o; o >>= 1) s += __shfl_down(s, o);
    if (lane == 0) sred[wid] = s;
    // intra-bucket exclusive scan of padded degrees (only waves 0,1 carry values)
    int v = (t < nn) ? ((cnt[n0 + t] + 7) & ~7) : 0;
    int x = v;
    for (int o = 1; o < 64; o <<= 1) {
        int y = __shfl_up(x, o);
        if (lane >= o) x += y;
    }
    if (lane == 63) wtot[wid] = x;
    __syncthreads();
    int base = sred[0] + sred[1] + sred[2] + sred[3] +
               sred[4] + sred[5] + sred[6] + sred[7];
    int add = (wid == 1) ? wtot[0] : 0;
    int excl = base + x - v + add;
    if (t < nn) {
        rbase[t] = excl;
        rowptr[n0 + t] = excl;
        cur[t] = 0;
    }
    int endoff = base + wtot[0] + wtot[1];     // rowptr[n1]
    if (b == nbkt - 1 && t == 0) rowptr[n] = endoff;
    __syncthreads();
    int beg = b << CAP_LOG;
    int fill = gbcur[b]; if (fill > CAP) fill = CAP;
    int end = beg + fill;
    int nv = fill >> 2;
    const int4* bb4 = (const int4*)(buck + beg);
#define SCAT(VV) { int ld_ = (VV) & (R_NODES - 1);                       \
                   int p_ = rbase[ld_] + atomicAdd(&cur[ld_], 1);        \
                   ew[p_] = (VV) >> R_LOG; }
    for (int i = t; i < nv; i += 512) {
        int4 vv = bb4[i];
        SCAT(vv.x) SCAT(vv.y) SCAT(vv.z) SCAT(vv.w)
    }
    for (int i = beg + (nv << 2) + t; i < end; i += 512) {
        int vv = buck[i];
        SCAT(vv)
    }
#undef SCAT
    __syncthreads();
    if (t < nn) {
        int pe = (t + 1 < nn) ? rbase[t + 1] : endoff;
        for (int j = rbase[t] + cur[t]; j < pe; ++j) ew[j] = n;   // zero-row src
    }
}

// --- layer-1 GEMM, persistent 2 tiles/block (256-row, 512 thr), W staged once ---------
// T1 = fp8( FS * (x @ W1) * dinv[row] ).
__device__ __forceinline__ void gemm1_persist(int bid, int ntiles,
                                              const float* __restrict__ Av,
                                              const float* __restrict__ W,
                                              const float* __restrict__ dinv,
                                              uchar* __restrict__ C, int n) {
    __shared__ ushort Wt[128 * 136];
    __shared__ uchar Cs[128 * 128];     // 16KB: one mt-half of fp8 output
    int t = threadIdx.x;
    for (int idx = t; idx < 128 * 128; idx += 512) {
        int k = idx >> 7, nn = idx & 127;
        Wt[nn * 136 + k] = f2bf(W[idx]);
    }
    __syncthreads();

    int w = t >> 6, l = t & 63;
    int lrow = l & 15, lhk = (l >> 4) * 8;
    int rb = (l >> 4) * 4;

    for (int ti = 0; ti < 2; ++ti) {
        int tile = bid * 2 + ti;
        if (tile >= ntiles) break;
        int r0 = tile * 256;

        short8 afrag[2][4];
        for (int mt = 0; mt < 2; ++mt) {
            int row = r0 + mt * 128 + w * 16 + lrow;
            bool ok = row < n;
            for (int ks = 0; ks < 4; ++ks) {
                int kb = ks * 32 + lhk;
                short8 f = {0, 0, 0, 0, 0, 0, 0, 0};
                if (ok) {
                    const float* ap = Av + (size_t)row * 128 + kb;
                    float4 u0 = *(const float4*)ap;
                    float4 u1 = *(const float4*)(ap + 4);
                    f[0] = (short)f2bf(u0.x); f[1] = (short)f2bf(u0.y);
                    f[2] = (short)f2bf(u0.z); f[3] = (short)f2bf(u0.w);
                    f[4] = (short)f2bf(u1.x); f[5] = (short)f2bf(u1.y);
                    f[6] = (short)f2bf(u1.z); f[7] = (short)f2bf(u1.w);
                }
                afrag[mt][ks] = f;
            }
        }

        f32x4 acc[2][8];
        for (int mt = 0; mt < 2; ++mt)
            for (int nt = 0; nt < 8; ++nt)
                acc[mt][nt] = (f32x4){0.f, 0.f, 0.f, 0.f};

#pragma unroll
        for (int ks = 0; ks < 4; ++ks)
#pragma unroll
            for (int nt = 0; nt < 8; ++nt) {
                short8 b = *(const short8*)&Wt[(nt * 16 + lrow) * 136 + ks * 32 + lhk];
                acc[0][nt] = __builtin_amdgcn_mfma_f32_16x16x32_bf16(afrag[0][ks], b, acc[0][nt], 0, 0, 0);
                acc[1][nt] = __builtin_amdgcn_mfma_f32_16x16x32_bf16(afrag[1][ks], b, acc[1][nt], 0, 0, 0);
            }

        for (int mt = 0; mt < 2; ++mt) {
            __syncthreads();                // Cs free (prev half stored / prev tile done)
            for (int r = 0; r < 4; ++r) {
                int lrh = w * 16 + rb + r;
                int rr = r0 + mt * 128 + lrh;
                float di = (rr < n) ? dinv[rr] * FS : 0.f;
                for (int nt = 0; nt < 8; ++nt) {
                    float v = acc[mt][nt][r] * di;
                    uint bb = (uint)__builtin_amdgcn_cvt_pk_fp8_f32(v, v, 0, false);
                    Cs[lrh * 128 + nt * 16 + lrow] = (uchar)(bb & 0xFF);
                }
            }
            __syncthreads();
            for (int idx = t; idx < 1024; idx += 512) {
                int rr = idx >> 3, cc = (idx & 7) * 16;
                int row2 = r0 + mt * 128 + rr;
                if (row2 < n)
                    *(uint4*)(C + (size_t)row2 * 128 + cc) = *(const uint4*)&Cs[rr * 128 + cc];
            }
        }
    }
}

// ------- fused: layer-1 GEMM persistent (blocks [0,ngem)) ∥ csr_pass (rest) -----------
__global__ __launch_bounds__(512) void csr_gemm1(const int* __restrict__ buck,
                                                 const int* __restrict__ cnt,
                                                 const int* __restrict__ bktsum,
                                                 const int* __restrict__ gbcur,
                                                 int n, int nbkt, int ngem, int ntiles,
                                                 int* __restrict__ ew,
                                                 int* __restrict__ rowptr,
                                                 const float* __restrict__ x,
                                                 const float* __restrict__ W1,
                                                 const float* __restrict__ dinv,
                                                 uchar* __restrict__ T1) {
    int b = blockIdx.x;
    if (b < ngem)
        gemm1_persist(b, ntiles, x, W1, dinv, T1, n);
    else
        csr_body(b - ngem, buck, cnt, bktsum, gbcur, n, nbkt, ew, rowptr);
}

// --- layer-2 GEMM persistent 2 tiles/block (256-row, 512 thr) + fused mean-pool -------
// out2[d] = relu(v'[d] @ W2 + b2) — accumulated per graph into gsum/gcnt; no C write.
__global__ __launch_bounds__(512) void gemm2_pool(const ushort* __restrict__ A,
                                                  const float* __restrict__ W,
                                                  const float* __restrict__ bias,
                                                  const int* __restrict__ batch,
                                                  float* __restrict__ gsum,
                                                  float* __restrict__ gcnt,
                                                  int n, int ntiles) {
    __shared__ ushort Wt[128 * 136];
    __shared__ float pg[2][128];
    __shared__ int bloc[256];
    __shared__ int cnt01[2];
    __shared__ int g01[2];
    int t = threadIdx.x;
    for (int idx = t; idx < 128 * 128; idx += 512) {
        int k = idx >> 7, nn = idx & 127;
        Wt[nn * 136 + k] = f2bf(W[idx]);
    }

    int w = t >> 6, l = t & 63;
    int lrow = l & 15, lhk = (l >> 4) * 8;
    int rb = (l >> 4) * 4;
    float bch[8];
#pragma unroll
    for (int nt = 0; nt < 8; ++nt) bch[nt] = bias[nt * 16 + lrow];

    for (int ti = 0; ti < 2; ++ti) {
        int tile = blockIdx.x * 2 + ti;
        if (tile >= ntiles) break;
        int r0 = tile * 256;

        __syncthreads();                 // pg/bloc free from previous tile
        if (t < 256) {
            int row = r0 + t;
            bloc[t] = (row < n) ? batch[row] : -1;
        }
        if (t < 128) { pg[0][t] = 0.f; pg[1][t] = 0.f; }
        if (t < 2) cnt01[t] = 0;
        __syncthreads();
        if (t == 0) {
            g01[0] = bloc[0];
            int j = 255; while (j > 0 && bloc[j] < 0) --j;
            g01[1] = bloc[j];
        }

        short8 afrag[2][4];
        for (int mt = 0; mt < 2; ++mt) {
            int row = r0 + mt * 128 + w * 16 + lrow;
            bool ok = row < n;
            for (int ks = 0; ks < 4; ++ks) {
                short8 f = {0, 0, 0, 0, 0, 0, 0, 0};
                if (ok) f = *(const short8*)(A + (size_t)row * 128 + ks * 32 + lhk);
                afrag[mt][ks] = f;
            }
        }

        f32x4 acc[2][8];
        for (int mt = 0; mt < 2; ++mt)
            for (int nt = 0; nt < 8; ++nt)
                acc[mt][nt] = (f32x4){0.f, 0.f, 0.f, 0.f};

#pragma unroll
        for (int ks = 0; ks < 4; ++ks)
#pragma unroll
            for (int nt = 0; nt < 8; ++nt) {
                short8 b = *(const short8*)&Wt[(nt * 16 + lrow) * 136 + ks * 32 + lhk];
                acc[0][nt] = __builtin_amdgcn_mfma_f32_16x16x32_bf16(afrag[0][ks], b, acc[0][nt], 0, 0, 0);
                acc[1][nt] = __builtin_amdgcn_mfma_f32_16x16x32_bf16(afrag[1][ks], b, acc[1][nt], 0, 0, 0);
            }
        __syncthreads();            // g01 visible to all

        int g0 = g01[0], g1 = g01[1];
        float ch0[8], ch1[8];
#pragma unroll
        for (int nt = 0; nt < 8; ++nt) { ch0[nt] = 0.f; ch1[nt] = 0.f; }
        int c0 = 0, c1 = 0;
        for (int mt = 0; mt < 2; ++mt)
            for (int r = 0; r < 4; ++r) {
                int lr = mt * 128 + w * 16 + rb + r;
                int rr = r0 + lr;
                if (rr >= n) continue;
                int g = bloc[lr];
                if (g == g0) {
#pragma unroll
                    for (int nt = 0; nt < 8; ++nt)
                        ch0[nt] += fmaxf(acc[mt][nt][r] + bch[nt], 0.f);
                    if (lrow == 0) c0++;
                } else if (g == g1) {
#pragma unroll
                    for (int nt = 0; nt < 8; ++nt)
                        ch1[nt] += fmaxf(acc[mt][nt][r] + bch[nt], 0.f);
                    if (lrow == 0) c1++;
                } else {                       // rare middle graph(s): direct atomics
#pragma unroll
                    for (int nt = 0; nt < 8; ++nt)
                        atomicAdd(&gsum[g * 128 + nt * 16 + lrow],
                                  fmaxf(acc[mt][nt][r] + bch[nt], 0.f));
                    if (lrow == 0) atomicAdd(&gcnt[g], 1.f);
                }
            }
#pragma unroll
        for (int nt = 0; nt < 8; ++nt) {
            int ch = nt * 16 + lrow;
            atomicAdd(&pg[0][ch], ch0[nt]);
            atomicAdd(&pg[1][ch], ch1[nt]);
        }
        if (lrow == 0) {
            if (c0) atomicAdd(&cnt01[0], c0);
            if (c1) atomicAdd(&cnt01[1], c1);
        }
        __syncthreads();
        if (t < 128) {
            atomicAdd(&gsum[g0 * 128 + t], pg[0][t]);
            if (g1 != g0) atomicAdd(&gsum[g1 * 128 + t], pg[1][t]);
        }
        if (t == 0) {
            atomicAdd(&gcnt[g0], (float)cnt01[0]);
            if (g1 != g0) atomicAdd(&gcnt[g1], (float)cnt01[1]);
        }
    }
}

// ----- aggregation: wave/node, 8-lane uint4 fp8 row gathers (8 rows / instruction) ----
// Each octet (8 lanes) reads one 128B row; lane covers channels (lane&7)*16..+15.
#define LDG4(s) (*(const uint4*)(xwb + ((((uint)(s)) << 7) + clo)))
#define ACCU(G)                                                             \
    { a0 += __builtin_amdgcn_cvt_pk_f32_fp8((int)(G).x, false);             \
      a1 += __builtin_amdgcn_cvt_pk_f32_fp8((int)(G).x, true);              \
      a2 += __builtin_amdgcn_cvt_pk_f32_fp8((int)(G).y, false);             \
      a3 += __builtin_amdgcn_cvt_pk_f32_fp8((int)(G).y, true);              \
      a4 += __builtin_amdgcn_cvt_pk_f32_fp8((int)(G).z, false);             \
      a5 += __builtin_amdgcn_cvt_pk_f32_fp8((int)(G).z, true);              \
      a6 += __builtin_amdgcn_cvt_pk_f32_fp8((int)(G).w, false);             \
      a7 += __builtin_amdgcn_cvt_pk_f32_fp8((int)(G).w, true); }

template <int MODE>
__global__ __launch_bounds__(256) void agg_gather(const uchar* __restrict__ tab,
                                                  const int* __restrict__ ewsrc,
                                                  const int* __restrict__ rowptr,
                                                  const float* __restrict__ dinv,
                                                  const float* __restrict__ bias,
                                                  void* __restrict__ outp, int n) {
    int node = blockIdx.x * 4 + (threadIdx.x >> 6);
    if (node >= n) return;
    int lane = threadIdx.x & 63;
    int oct = lane >> 3;               // octet 0..7: one row each per gather instr
    int cl8 = lane & 7;                // channels cl8*16 .. cl8*16+15
    const char* xwb = (const char*)tab;
    uint clo = (uint)cl8 << 4;
    f32x2 a0 = {0.f, 0.f}, a1 = {0.f, 0.f}, a2 = {0.f, 0.f}, a3 = {0.f, 0.f};
    f32x2 a4 = {0.f, 0.f}, a5 = {0.f, 0.f}, a6 = {0.f, 0.f}, a7 = {0.f, 0.f};
    int beg = rowptr[node], end = rowptr[node + 1];   // multiple of 8 apart
    int d8 = end - beg;                               // wave-uniform padded degree

    if (d8 <= 32) {
        // fast path (covers ~all nodes): issue every gather before any accumulate
        int sv = ewsrc[beg + (lane & 31)];
        int ng = d8 >> 3;                              // 0..4 groups of 8 slots
        uint4 A, B, C, D;
        if (ng > 0) { int s = __shfl(sv, oct);      A = LDG4(s); }
        if (ng > 1) { int s = __shfl(sv, 8 + oct);  B = LDG4(s); }
        if (ng > 2) { int s = __shfl(sv, 16 + oct); C = LDG4(s); }
        if (ng > 3) { int s = __shfl(sv, 24 + oct); D = LDG4(s); }
        if (ng > 0) { ACCU(A); }
        if (ng > 1) { ACCU(B); }
        if (ng > 2) { ACCU(C); }
        if (ng > 3) { ACCU(D); }
    } else {
        // rare heavy nodes: depth-2 pipelined chunks of 64 slots (8 groups)
        for (int c = beg; c < end; c += 64) {
            int sv = ewsrc[c + lane];
            int ce = c + 64 < end ? c + 64 : end;
            int ngr = (ce - c) >> 3;
            uint4 A = LDG4(__shfl(sv, oct));
            for (int g = 1; g < ngr; ++g) {
                uint4 B = LDG4(__shfl(sv, g * 8 + oct));
                ACCU(A);
                A = B;
            }
            ACCU(A);
        }
    }

    // reduce across the 8 octets (lanes cl8, cl8+8, ..., cl8+56)
    a0 += shx2(a0, 8);  a1 += shx2(a1, 8);  a2 += shx2(a2, 8);  a3 += shx2(a3, 8);
    a4 += shx2(a4, 8);  a5 += shx2(a5, 8);  a6 += shx2(a6, 8);  a7 += shx2(a7, 8);
    a0 += shx2(a0, 16); a1 += shx2(a1, 16); a2 += shx2(a2, 16); a3 += shx2(a3, 16);
    a4 += shx2(a4, 16); a5 += shx2(a5, 16); a6 += shx2(a6, 16); a7 += shx2(a7, 16);
    a0 += shx2(a0, 32); a1 += shx2(a1, 32); a2 += shx2(a2, 32); a3 += shx2(a3, 32);
    a4 += shx2(a4, 32); a5 += shx2(a5, 32); a6 += shx2(a6, 32); a7 += shx2(a7, 32);
    if (lane < 8) {
        float di = dinv[node];
        float diS = di * FSI;
        uint4 sv4 = LDG4(node);                       // self term (already scaled)
        f32x2 s0 = __builtin_amdgcn_cvt_pk_f32_fp8((int)sv4.x, false);
        f32x2 s1 = __builtin_amdgcn_cvt_pk_f32_fp8((int)sv4.x, true);
        f32x2 s2 = __builtin_amdgcn_cvt_pk_f32_fp8((int)sv4.y, false);
        f32x2 s3 = __builtin_amdgcn_cvt_pk_f32_fp8((int)sv4.y, true);
        f32x2 s4 = __builtin_amdgcn_cvt_pk_f32_fp8((int)sv4.z, false);
        f32x2 s5 = __builtin_amdgcn_cvt_pk_f32_fp8((int)sv4.z, true);
        f32x2 s6 = __builtin_amdgcn_cvt_pk_f32_fp8((int)sv4.w, false);
        f32x2 s7 = __builtin_amdgcn_cvt_pk_f32_fp8((int)sv4.w, true);
        if constexpr (MODE == 0) {
            const float4* b4 = (const float4*)bias;
            float4 bb0 = b4[cl8 * 4], bb1 = b4[cl8 * 4 + 1];
            float4 bb2 = b4[cl8 * 4 + 2], bb3 = b4[cl8 * 4 + 3];
            float So = FS * di;
            float v0 = fmaxf(diS * (a0.x + s0.x) + bb0.x, 0.f) * So;
            float v1 = fmaxf(diS * (a0.y + s0.y) + bb0.y, 0.f) * So;
            float v2 = fmaxf(diS * (a1.x + s1.x) + bb0.z, 0.f) * So;
            float v3 = fmaxf(diS * (a1.y + s1.y) + bb0.w, 0.f) * So;
            float v4 = fmaxf(diS * (a2.x + s2.x) + bb1.x, 0.f) * So;
            float v5 = fmaxf(diS * (a2.y + s2.y) + bb1.y, 0.f) * So;
            float v6 = fmaxf(diS * (a3.x + s3.x) + bb1.z, 0.f) * So;
            float v7 = fmaxf(diS * (a3.y + s3.y) + bb1.w, 0.f) * So;
            float v8 = fmaxf(diS * (a4.x + s4.x) + bb2.x, 0.f) * So;
            float v9 = fmaxf(diS * (a4.y + s4.y) + bb2.y, 0.f) * So;
            float vA = fmaxf(diS * (a5.x + s5.x) + bb2.z, 0.f) * So;
            float vB = fmaxf(diS * (a5.y + s5.y) + bb2.w, 0.f) * So;
            float vC = fmaxf(diS * (a6.x + s6.x) + bb3.x, 0.f) * So;
            float vD = fmaxf(diS * (a6.y + s6.y) + bb3.y, 0.f) * So;
            float vE = fmaxf(diS * (a7.x + s7.x) + bb3.z, 0.f) * So;
            float vF = fmaxf(diS * (a7.y + s7.y) + bb3.w, 0.f) * So;
            uint4 r;
            uint u = (uint)__builtin_amdgcn_cvt_pk_fp8_f32(v0, v1, 0, false);
            r.x = (uint)__builtin_amdgcn_cvt_pk_fp8_f32(v2, v3, (int)u, true);
            u = (uint)__builtin_amdgcn_cvt_pk_fp8_f32(v4, v5, 0, false);
            r.y = (uint)__builtin_amdgcn_cvt_pk_fp8_f32(v6, v7, (int)u, true);
            u = (uint)__builtin_amdgcn_cvt_pk_fp8_f32(v8, v9, 0, false);
            r.z = (uint)__builtin_amdgcn_cvt_pk_fp8_f32(vA, vB, (int)u, true);
            u = (uint)__builtin_amdgcn_cvt_pk_fp8_f32(vC, vD, 0, false);
            r.w = (uint)__builtin_amdgcn_cvt_pk_fp8_f32(vE, vF, (int)u, true);
            *(uint4*)((char*)outp + ((size_t)node << 7) + clo) = r;
        } else {
            float v0 = diS * (a0.x + s0.x), v1 = diS * (a0.y + s0.y);
            float v2 = diS * (a1.x + s1.x), v3 = diS * (a1.y + s1.y);
            float v4 = diS * (a2.x + s2.x), v5 = diS * (a2.y + s2.y);
            float v6 = diS * (a3.x + s3.x), v7 = diS * (a3.y + s3.y);
            float v8 = diS * (a4.x + s4.x), v9 = diS * (a4.y + s4.y);
            float vA = diS * (a5.x + s5.x), vB = diS * (a5.y + s5.y);
            float vC = diS * (a6.x + s6.x), vD = diS * (a6.y + s6.y);
            float vE = diS * (a7.x + s7.x), vF = diS * (a7.y + s7.y);
            uint4 r0, r1;
            r0.x = (uint)f2bf(v0) | ((uint)f2bf(v1) << 16);
            r0.y = (uint)f2bf(v2) | ((uint)f2bf(v3) << 16);
            r0.z = (uint)f2bf(v4) | ((uint)f2bf(v5) << 16);
            r0.w = (uint)f2bf(v6) | ((uint)f2bf(v7) << 16);
            r1.x = (uint)f2bf(v8) | ((uint)f2bf(v9) << 16);
            r1.y = (uint)f2bf(vA) | ((uint)f2bf(vB) << 16);
            r1.z = (uint)f2bf(vC) | ((uint)f2bf(vD) << 16);
            r1.w = (uint)f2bf(vE) | ((uint)f2bf(vF) << 16);
            ((uint4*)outp)[(size_t)node * 16 + cl8 * 2] = r0;
            ((uint4*)outp)[(size_t)node * 16 + cl8 * 2 + 1] = r1;
        }
    }
}

// ---------------- head ----------------
__global__ __launch_bounds__(128) void final_kernel(const float* __restrict__ gsum,
                                                    const float* __restrict__ gcnt,
                                                    const float* __restrict__ Wlin,
                                                    const float* __restrict__ blin,
                                                    float* __restrict__ out) {
    __shared__ float pooled[128];
    int g = blockIdx.x;
    int c = threadIdx.x;
    float cntv = gcnt[g]; if (cntv < 1.f) cntv = 1.f;
    pooled[c] = gsum[g * 128 + c] / cntv;
    __syncthreads();
    if (c < 10) {
        float acc = blin[c];
        for (int k = 0; k < 128; ++k) acc += pooled[k] * Wlin[k * 10 + c];
        out[g * 10 + c] = acc;
    }
}

extern "C" void kernel_launch(void* const* d_in, const int* in_sizes, int n_in,
                              void* d_out, int out_size, void* d_ws, size_t ws_size,
                              hipStream_t stream) {
    const float* x    = (const float*)d_in[0];
    const int*   ei   = (const int*)d_in[1];
    const int*   batch= (const int*)d_in[2];
    const float* W1   = (const float*)d_in[3];
    const float* b1   = (const float*)d_in[4];
    const float* W2   = (const float*)d_in[5];
    const float* b2   = (const float*)d_in[6];
    const float* Wlin = (const float*)d_in[7];
    const float* blin = (const float*)d_in[8];
    float* out = (float*)d_out;

    const int n = in_sizes[0] / 128;
    const int e = in_sizes[1] / 2;
    const int* src = ei;
    const int* dst = ei + e;
    const int nb_bkt = (n + R_NODES - 1) >> R_LOG;

    char* ws = (char*)d_ws;
    size_t off = 0;
    auto take = [&](size_t bytes) -> char* {
        char* p = ws + off;
        off = (off + bytes + 255) & ~(size_t)255;
        return p;
    };
    int*    rowptr = (int*)   take((size_t)(n + 1) * 4);
    int*    cnt    = (int*)   take((size_t)n * 4);
    float*  dinv   = (float*) take((size_t)n * 4);
    int*    bktsum = (int*)   take((size_t)NB_MAX * 4);
    int*    ewsrc  = (int*)   take(((size_t)e + 7ull * (size_t)n + 64) * 4);  // padded CSR
    uchar*  T1     = (uchar*) take((size_t)(n + 1) * 128);   // fp8 table L1 (+pad row)
    uchar*  T2     = (uchar*) take((size_t)(n + 1) * 128);   // fp8 table L2 (+pad row)
    ushort* V      = (ushort*)take((size_t)n * 128 * 2);     // bf16 v' (GEMM2 input)
    // zero-init block: gbcur | gsum | gcnt — contiguous, one memset
    int*    gbcur  = (int*)   take((size_t)NB_MAX * 4);
    float*  gsum   = (float*) take(64 * 128 * 4);
    float*  gcnt   = (float*) take(64 * 4);
    (void)ws_size;
    int* buck = (int*)V;    // alias: 12.8MB <= 25.6MB; consumed before agg2 writes V

    size_t zspan = (size_t)((char*)gcnt + 64 * 4 - (char*)gbcur);
    hipMemsetAsync(gbcur, 0, zspan, stream);

    bin_pass<<<(e + CH - 1) / CH, 1024, 0, stream>>>(src, dst, e, gbcur, buck, nb_bkt);
    count_pass<<<nb_bkt, 256, 0, stream>>>(buck, gbcur, cnt, dinv, bktsum,
                                           (uint*)(T1 + (size_t)n * 128),
                                           (uint*)(T2 + (size_t)n * 128), n);

    const int ntiles = (n + 255) / 256;
    const int ngem = (ntiles + 1) / 2;
    csr_gemm1<<<ngem + nb_bkt, 512, 0, stream>>>(buck, cnt, bktsum, gbcur, n, nb_bkt,
                                                 ngem, ntiles, ewsrc, rowptr,
                                                 x, W1, dinv, T1);

    // layer 1 aggregate: T2 = fp8(FS*dinv*relu(dinv*(sum+self)/FS + b1))
    agg_gather<0><<<(n + 3) / 4, 256, 0, stream>>>(T1, ewsrc, rowptr, dinv, b1, T2, n);
    // layer 2 aggregate (commuted): v' = dinv*(sum+self)/FS, bf16
    agg_gather<1><<<(n + 3) / 4, 256, 0, stream>>>(T2, ewsrc, rowptr, dinv, b1, V, n);
    // layer 2 GEMM + relu + mean-pool (writes only pooled atomics)
    gemm2_pool<<<ngem, 512, 0, stream>>>(V, W2, b2, batch, gsum, gcnt, n, ntiles);

    final_kernel<<<64, 128, 0, stream>>>(gsum, gcnt, Wlin, blin, out);
}

// Round 14
// 174.059 us; speedup vs baseline: 1.2077x; 1.2077x over previous
//
#include <hip/hip_runtime.h>

// GCN 2-layer. CSR via fixed-capacity bucketed counting sort, csr_pass fused with
// layer-1 MFMA GEMM (gemm blocks first, 2 tiles/block, W staged once), dinv folded
// into epilogues. Layer-2 COMMUTED (aggregate-then-GEMM) with mean-pool fused into
// GEMM2 epilogue (2 tiles/block persistent). fp8-e4m3 gather tables (x16).
// agg: 16-lane uint2 gathers, TWO nodes per wave (<=16 gathers in flight before
// any accumulate — doubled memory-level parallelism). 8 dispatches.

#define TPB 256
#define R_LOG 7
#define R_NODES 128          // nodes per bucket
#define NB_MAX 800           // >= ceil(100000/128)=782
#define CH 8192              // edges per bin_pass block
#define CAP_LOG 12
#define CAP 4096             // bucket capacity (avg fill ~2048 for E=1.6M, N=100K)

#define FS 16.0f             // fp8 table scale
#define FSI (1.0f / 16.0f)

typedef __attribute__((ext_vector_type(8))) short short8;
typedef __attribute__((ext_vector_type(4))) float f32x4;
typedef __attribute__((ext_vector_type(2))) float f32x2;

__device__ inline ushort f2bf(float x) {
    uint u = __float_as_uint(x);
    return (ushort)((u + 0x7FFFu + ((u >> 16) & 1u)) >> 16);   // RTNE
}

__device__ inline f32x2 shx2(f32x2 v, int m) {
    double d = __shfl_xor(__builtin_bit_cast(double, v), m);
    return __builtin_bit_cast(f32x2, d);
}

// ---------------- pass A: bin edges into fixed-cap 128-node buckets (packed) ----------
__global__ __launch_bounds__(1024) void bin_pass(const int* __restrict__ src,
                                                 const int* __restrict__ dst, int e,
                                                 int* __restrict__ gbcur,
                                                 int* __restrict__ buck, int nb) {
    __shared__ int vloc[CH];            // packed (src<<7)|(dst&127)
    __shared__ ushort bidl[CH];         // bucket id
    __shared__ int cnts[NB_MAX], starts[NB_MAX], cnts2[NB_MAX];
    int t = threadIdx.x;
    for (int i = t; i < nb; i += 1024) { cnts[i] = 0; cnts2[i] = 0; }
    __syncthreads();
    int base = blockIdx.x * CH;
    int lim = base + CH; if (lim > e) lim = e;
    int ce = lim - base;
    int nv = ce >> 2;
    const int4* s4 = (const int4*)(src + base);
    const int4* d4 = (const int4*)(dst + base);
    for (int i = t; i < nv; i += 1024) {
        int4 s = s4[i], d = d4[i];
        int j = i << 2;
#define BIN1(J, SS, DD)                                                      \
        { int b_ = (DD) >> R_LOG;                                            \
          vloc[J] = ((SS) << R_LOG) | ((DD) & (R_NODES - 1));                \
          bidl[J] = (ushort)b_;                                              \
          atomicAdd(&cnts[b_], 1); }
        BIN1(j,     s.x, d.x)
        BIN1(j + 1, s.y, d.y)
        BIN1(j + 2, s.z, d.z)
        BIN1(j + 3, s.w, d.w)
    }
    for (int j = (nv << 2) + t; j < ce; j += 1024) {
        int dv = dst[base + j], sv = src[base + j];
        BIN1(j, sv, dv)
    }
#undef BIN1
    __syncthreads();
    for (int i = t; i < nb; i += 1024) {
        int c = cnts[i];
        starts[i] = c ? ((i << CAP_LOG) + atomicAdd(&gbcur[i], c)) : 0;
    }
    __syncthreads();
    for (int j = t; j < ce; j += 1024) {
        int b = bidl[j];
        int pos = starts[b] + atomicAdd(&cnts2[b], 1);
        if (pos < ((b + 1) << CAP_LOG))                    // overflow clamp (never hit)
            buck[pos] = vloc[j];
    }
}

// ------- degree count per bucket (LDS histogram, int4 reads) + padded sum -------
__global__ __launch_bounds__(256) void count_pass(const int* __restrict__ buck,
                                                  const int* __restrict__ gbcur,
                                                  int* __restrict__ cnt,
                                                  float* __restrict__ dinv,
                                                  int* __restrict__ bktsum,
                                                  uint* __restrict__ t1z,
                                                  uint* __restrict__ t2z, int n) {
    __shared__ int c128[R_NODES];
    __shared__ int wred[4];
    int t = threadIdx.x;
    int b = blockIdx.x;
    if (b == 0 && t < 32) { t1z[t] = 0; t2z[t] = 0; }      // zero rows for pad slots
    if (t < R_NODES) c128[t] = 0;
    __syncthreads();
    int beg = b << CAP_LOG;
    int fill = gbcur[b]; if (fill > CAP) fill = CAP;
    int end = beg + fill;
    int nv = fill >> 2;
    const int4* b4 = (const int4*)(buck + beg);
    for (int i = t; i < nv; i += 256) {
        int4 v = b4[i];
        atomicAdd(&c128[v.x & (R_NODES - 1)], 1);
        atomicAdd(&c128[v.y & (R_NODES - 1)], 1);
        atomicAdd(&c128[v.z & (R_NODES - 1)], 1);
        atomicAdd(&c128[v.w & (R_NODES - 1)], 1);
    }
    for (int i = beg + (nv << 2) + t; i < end; i += 256)
        atomicAdd(&c128[buck[i] & (R_NODES - 1)], 1);
    __syncthreads();
    int node = (b << R_LOG) + t;
    int pv = 0;
    if (t < R_NODES && node < n) {
        int c = c128[t];
        cnt[node] = c;
        dinv[node] = rsqrtf((float)(c + 1));   // +1 self loop
        pv = (c + 7) & ~7;                      // padded degree
    }
    for (int o = 32; o; o >>= 1) pv += __shfl_down(pv, o);
    int lane = t & 63, wid = t >> 6;
    if (lane == 0) wred[wid] = pv;
    __syncthreads();
    if (t == 0) bktsum[b] = wred[0] + wred[1] + wred[2] + wred[3];
}

// ------ csr body (512-thread): self-scan base + intra-bucket prefix + scatter + pad ---
__device__ __forceinline__ void csr_body(int b, const int* __restrict__ buck,
                                         const int* __restrict__ cnt,
                                         const int* __restrict__ bktsum,
                                         const int* __restrict__ gbcur,
                                         int n, int nbkt, int* __restrict__ ew,
                                         int* __restrict__ rowptr) {
    __shared__ int rbase[R_NODES];
    __shared__ int cur[R_NODES];
    __shared__ int wtot[8], sred[8];
    int t = threadIdx.x;
    int n0 = b << R_LOG;
    int n1 = n0 + R_NODES; if (n1 > n) n1 = n;
    int nn = n1 - n0;
    int lane = t & 63, wid = t >> 6;
    // base = sum of bktsum[0..b)  (<=2 coalesced loads/thread, L2-hot)
    int s = 0;
    for (int i = t; i < b; i += 512) s += bktsum[i];
    for (int o = 32; o; o >>= 1) s += __shfl_down(s, o);
    if (lane == 0) sred[wid] = s;
    // intra-bucket exclusive scan of padded degrees (only waves 0,1 carry values)
    int v = (t < nn) ? ((cnt[n0 + t] + 7) & ~7) : 0;
    int x = v;
    for (int o = 1; o < 64; o <<= 1) {
        int y = __shfl_up(x, o);
        if (lane >= o) x += y;
    }
    if (lane == 63) wtot[wid] = x;
    __syncthreads();
    int base = sred[0] + sred[1] + sred[2] + sred[3] +
               sred[4] + sred[5] + sred[6] + sred[7];
    int add = (wid == 1) ? wtot[0] : 0;
    int excl = base + x - v + add;
    if (t < nn) {
        rbase[t] = excl;
        rowptr[n0 + t] = excl;
        cur[t] = 0;
    }
    int endoff = base + wtot[0] + wtot[1];     // rowptr[n1]
    if (b == nbkt - 1 && t == 0) rowptr[n] = endoff;
    __syncthreads();
    int beg = b << CAP_LOG;
    int fill = gbcur[b]; if (fill > CAP) fill = CAP;
    int end = beg + fill;
    int nv = fill >> 2;
    const int4* bb4 = (const int4*)(buck + beg);
#define SCAT(VV) { int ld_ = (VV) & (R_NODES - 1);                       \
                   int p_ = rbase[ld_] + atomicAdd(&cur[ld_], 1);        \
                   ew[p_] = (VV) >> R_LOG; }
    for (int i = t; i < nv; i += 512) {
        int4 vv = bb4[i];
        SCAT(vv.x) SCAT(vv.y) SCAT(vv.z) SCAT(vv.w)
    }
    for (int i = beg + (nv << 2) + t; i < end; i += 512) {
        int vv = buck[i];
        SCAT(vv)
    }
#undef SCAT
    __syncthreads();
    if (t < nn) {
        int pe = (t + 1 < nn) ? rbase[t + 1] : endoff;
        for (int j = rbase[t] + cur[t]; j < pe; ++j) ew[j] = n;   // zero-row src
    }
}

// --- layer-1 GEMM, persistent 2 tiles/block (256-row, 512 thr), W staged once ---------
// T1 = fp8( FS * (x @ W1) * dinv[row] ).
__device__ __forceinline__ void gemm1_persist(int bid, int ntiles,
                                              const float* __restrict__ Av,
                                              const float* __restrict__ W,
                                              const float* __restrict__ dinv,
                                              uchar* __restrict__ C, int n) {
    __shared__ ushort Wt[128 * 136];
    __shared__ uchar Cs[128 * 128];     // 16KB: one mt-half of fp8 output
    int t = threadIdx.x;
    for (int idx = t; idx < 128 * 128; idx += 512) {
        int k = idx >> 7, nn = idx & 127;
        Wt[nn * 136 + k] = f2bf(W[idx]);
    }
    __syncthreads();

    int w = t >> 6, l = t & 63;
    int lrow = l & 15, lhk = (l >> 4) * 8;
    int rb = (l >> 4) * 4;

    for (int ti = 0; ti < 2; ++ti) {
        int tile = bid * 2 + ti;
        if (tile >= ntiles) break;
        int r0 = tile * 256;

        short8 afrag[2][4];
        for (int mt = 0; mt < 2; ++mt) {
            int row = r0 + mt * 128 + w * 16 + lrow;
            bool ok = row < n;
            for (int ks = 0; ks < 4; ++ks) {
                int kb = ks * 32 + lhk;
                short8 f = {0, 0, 0, 0, 0, 0, 0, 0};
                if (ok) {
                    const float* ap = Av + (size_t)row * 128 + kb;
                    float4 u0 = *(const float4*)ap;
                    float4 u1 = *(const float4*)(ap + 4);
                    f[0] = (short)f2bf(u0.x); f[1] = (short)f2bf(u0.y);
                    f[2] = (short)f2bf(u0.z); f[3] = (short)f2bf(u0.w);
                    f[4] = (short)f2bf(u1.x); f[5] = (short)f2bf(u1.y);
                    f[6] = (short)f2bf(u1.z); f[7] = (short)f2bf(u1.w);
                }
                afrag[mt][ks] = f;
            }
        }

        f32x4 acc[2][8];
        for (int mt = 0; mt < 2; ++mt)
            for (int nt = 0; nt < 8; ++nt)
                acc[mt][nt] = (f32x4){0.f, 0.f, 0.f, 0.f};

#pragma unroll
        for (int ks = 0; ks < 4; ++ks)
#pragma unroll
            for (int nt = 0; nt < 8; ++nt) {
                short8 b = *(const short8*)&Wt[(nt * 16 + lrow) * 136 + ks * 32 + lhk];
                acc[0][nt] = __builtin_amdgcn_mfma_f32_16x16x32_bf16(afrag[0][ks], b, acc[0][nt], 0, 0, 0);
                acc[1][nt] = __builtin_amdgcn_mfma_f32_16x16x32_bf16(afrag[1][ks], b, acc[1][nt], 0, 0, 0);
            }

        for (int mt = 0; mt < 2; ++mt) {
            __syncthreads();                // Cs free (prev half stored / prev tile done)
            for (int r = 0; r < 4; ++r) {
                int lrh = w * 16 + rb + r;
                int rr = r0 + mt * 128 + lrh;
                float di = (rr < n) ? dinv[rr] * FS : 0.f;
                for (int nt = 0; nt < 8; ++nt) {
                    float v = acc[mt][nt][r] * di;
                    uint bb = (uint)__builtin_amdgcn_cvt_pk_fp8_f32(v, v, 0, false);
                    Cs[lrh * 128 + nt * 16 + lrow] = (uchar)(bb & 0xFF);
                }
            }
            __syncthreads();
            for (int idx = t; idx < 1024; idx += 512) {
                int rr = idx >> 3, cc = (idx & 7) * 16;
                int row2 = r0 + mt * 128 + rr;
                if (row2 < n)
                    *(uint4*)(C + (size_t)row2 * 128 + cc) = *(const uint4*)&Cs[rr * 128 + cc];
            }
        }
    }
}

// ------- fused: layer-1 GEMM persistent (blocks [0,ngem)) ∥ csr_pass (rest) -----------
__global__ __launch_bounds__(512) void csr_gemm1(const int* __restrict__ buck,
                                                 const int* __restrict__ cnt,
                                                 const int* __restrict__ bktsum,
                                                 const int* __restrict__ gbcur,
                                                 int n, int nbkt, int ngem, int ntiles,
                                                 int* __restrict__ ew,
                                                 int* __restrict__ rowptr,
                                                 const float* __restrict__ x,
                                                 const float* __restrict__ W1,
                                                 const float* __restrict__ dinv,
                                                 uchar* __restrict__ T1) {
    int b = blockIdx.x;
    if (b < ngem)
        gemm1_persist(b, ntiles, x, W1, dinv, T1, n);
    else
        csr_body(b - ngem, buck, cnt, bktsum, gbcur, n, nbkt, ew, rowptr);
}

// --- layer-2 GEMM persistent 2 tiles/block (256-row, 512 thr) + fused mean-pool -------
// out2[d] = relu(v'[d] @ W2 + b2) — accumulated per graph into gsum/gcnt; no C write.
__global__ __launch_bounds__(512) void gemm2_pool(const ushort* __restrict__ A,
                                                  const float* __restrict__ W,
                                                  const float* __restrict__ bias,
                                                  const int* __restrict__ batch,
                                                  float* __restrict__ gsum,
                                                  float* __restrict__ gcnt,
                                                  int n, int ntiles) {
    __shared__ ushort Wt[128 * 136];
    __shared__ float pg[2][128];
    __shared__ int bloc[256];
    __shared__ int cnt01[2];
    __shared__ int g01[2];
    int t = threadIdx.x;
    for (int idx = t; idx < 128 * 128; idx += 512) {
        int k = idx >> 7, nn = idx & 127;
        Wt[nn * 136 + k] = f2bf(W[idx]);
    }

    int w = t >> 6, l = t & 63;
    int lrow = l & 15, lhk = (l >> 4) * 8;
    int rb = (l >> 4) * 4;
    float bch[8];
#pragma unroll
    for (int nt = 0; nt < 8; ++nt) bch[nt] = bias[nt * 16 + lrow];

    for (int ti = 0; ti < 2; ++ti) {
        int tile = blockIdx.x * 2 + ti;
        if (tile >= ntiles) break;
        int r0 = tile * 256;

        __syncthreads();                 // pg/bloc free from previous tile
        if (t < 256) {
            int row = r0 + t;
            bloc[t] = (row < n) ? batch[row] : -1;
        }
        if (t < 128) { pg[0][t] = 0.f; pg[1][t] = 0.f; }
        if (t < 2) cnt01[t] = 0;
        __syncthreads();
        if (t == 0) {
            g01[0] = bloc[0];
            int j = 255; while (j > 0 && bloc[j] < 0) --j;
            g01[1] = bloc[j];
        }

        short8 afrag[2][4];
        for (int mt = 0; mt < 2; ++mt) {
            int row = r0 + mt * 128 + w * 16 + lrow;
            bool ok = row < n;
            for (int ks = 0; ks < 4; ++ks) {
                short8 f = {0, 0, 0, 0, 0, 0, 0, 0};
                if (ok) f = *(const short8*)(A + (size_t)row * 128 + ks * 32 + lhk);
                afrag[mt][ks] = f;
            }
        }

        f32x4 acc[2][8];
        for (int mt = 0; mt < 2; ++mt)
            for (int nt = 0; nt < 8; ++nt)
                acc[mt][nt] = (f32x4){0.f, 0.f, 0.f, 0.f};

#pragma unroll
        for (int ks = 0; ks < 4; ++ks)
#pragma unroll
            for (int nt = 0; nt < 8; ++nt) {
                short8 b = *(const short8*)&Wt[(nt * 16 + lrow) * 136 + ks * 32 + lhk];
                acc[0][nt] = __builtin_amdgcn_mfma_f32_16x16x32_bf16(afrag[0][ks], b, acc[0][nt], 0, 0, 0);
                acc[1][nt] = __builtin_amdgcn_mfma_f32_16x16x32_bf16(afrag[1][ks], b, acc[1][nt], 0, 0, 0);
            }
        __syncthreads();            // g01 visible to all

        int g0 = g01[0], g1 = g01[1];
        float ch0[8], ch1[8];
#pragma unroll
        for (int nt = 0; nt < 8; ++nt) { ch0[nt] = 0.f; ch1[nt] = 0.f; }
        int c0 = 0, c1 = 0;
        for (int mt = 0; mt < 2; ++mt)
            for (int r = 0; r < 4; ++r) {
                int lr = mt * 128 + w * 16 + rb + r;
                int rr = r0 + lr;
                if (rr >= n) continue;
                int g = bloc[lr];
                if (g == g0) {
#pragma unroll
                    for (int nt = 0; nt < 8; ++nt)
                        ch0[nt] += fmaxf(acc[mt][nt][r] + bch[nt], 0.f);
                    if (lrow == 0) c0++;
                } else if (g == g1) {
#pragma unroll
                    for (int nt = 0; nt < 8; ++nt)
                        ch1[nt] += fmaxf(acc[mt][nt][r] + bch[nt], 0.f);
                    if (lrow == 0) c1++;
                } else {                       // rare middle graph(s): direct atomics
#pragma unroll
                    for (int nt = 0; nt < 8; ++nt)
                        atomicAdd(&gsum[g * 128 + nt * 16 + lrow],
                                  fmaxf(acc[mt][nt][r] + bch[nt], 0.f));
                    if (lrow == 0) atomicAdd(&gcnt[g], 1.f);
                }
            }
#pragma unroll
        for (int nt = 0; nt < 8; ++nt) {
            int ch = nt * 16 + lrow;
            atomicAdd(&pg[0][ch], ch0[nt]);
            atomicAdd(&pg[1][ch], ch1[nt]);
        }
        if (lrow == 0) {
            if (c0) atomicAdd(&cnt01[0], c0);
            if (c1) atomicAdd(&cnt01[1], c1);
        }
        __syncthreads();
        if (t < 128) {
            atomicAdd(&gsum[g0 * 128 + t], pg[0][t]);
            if (g1 != g0) atomicAdd(&gsum[g1 * 128 + t], pg[1][t]);
        }
        if (t == 0) {
            atomicAdd(&gcnt[g0], (float)cnt01[0]);
            if (g1 != g0) atomicAdd(&gcnt[g1], (float)cnt01[1]);
        }
    }
}

// ---------------- aggregation: 2 nodes/wave, 16-lane uint2 fp8 gathers ----------------
#define LDG2(s) (*(const uint2*)(xwb + ((((uint)(s)) << 7) + clo)))
#define ACCU(G)                                                             \
    { a01 += __builtin_amdgcn_cvt_pk_f32_fp8((int)(G).x, false);            \
      a23 += __builtin_amdgcn_cvt_pk_f32_fp8((int)(G).x, true);             \
      a45 += __builtin_amdgcn_cvt_pk_f32_fp8((int)(G).y, false);            \
      a67 += __builtin_amdgcn_cvt_pk_f32_fp8((int)(G).y, true); }

// shuffle-reduce across quarters + epilogue store for one node
template <int MODE>
__device__ __forceinline__ void agg_finish(f32x2 a01, f32x2 a23, f32x2 a45, f32x2 a67,
                                           int node, int lane, int cl,
                                           const char* __restrict__ xwb, uint clo,
                                           const float* __restrict__ dinv,
                                           const float* __restrict__ bias,
                                           void* __restrict__ outp) {
    a01 += shx2(a01, 16); a23 += shx2(a23, 16);
    a45 += shx2(a45, 16); a67 += shx2(a67, 16);
    a01 += shx2(a01, 32); a23 += shx2(a23, 32);
    a45 += shx2(a45, 32); a67 += shx2(a67, 32);
    if (lane < 16) {
        float di = dinv[node];
        float diS = di * FSI;
        uint2 sv2 = LDG2(node);                       // self term (already scaled)
        f32x2 s01 = __builtin_amdgcn_cvt_pk_f32_fp8((int)sv2.x, false);
        f32x2 s23 = __builtin_amdgcn_cvt_pk_f32_fp8((int)sv2.x, true);
        f32x2 s45 = __builtin_amdgcn_cvt_pk_f32_fp8((int)sv2.y, false);
        f32x2 s67 = __builtin_amdgcn_cvt_pk_f32_fp8((int)sv2.y, true);
        if constexpr (MODE == 0) {
            const float4* b4 = (const float4*)bias;
            float4 bb0 = b4[cl * 2], bb1 = b4[cl * 2 + 1];
            float So = FS * di;
            float v0 = fmaxf(diS * (a01.x + s01.x) + bb0.x, 0.f) * So;
            float v1 = fmaxf(diS * (a01.y + s01.y) + bb0.y, 0.f) * So;
            float v2 = fmaxf(diS * (a23.x + s23.x) + bb0.z, 0.f) * So;
            float v3 = fmaxf(diS * (a23.y + s23.y) + bb0.w, 0.f) * So;
            float v4 = fmaxf(diS * (a45.x + s45.x) + bb1.x, 0.f) * So;
            float v5 = fmaxf(diS * (a45.y + s45.y) + bb1.y, 0.f) * So;
            float v6 = fmaxf(diS * (a67.x + s67.x) + bb1.z, 0.f) * So;
            float v7 = fmaxf(diS * (a67.y + s67.y) + bb1.w, 0.f) * So;
            uint lo = (uint)__builtin_amdgcn_cvt_pk_fp8_f32(v0, v1, 0, false);
            lo = (uint)__builtin_amdgcn_cvt_pk_fp8_f32(v2, v3, (int)lo, true);
            uint hi = (uint)__builtin_amdgcn_cvt_pk_fp8_f32(v4, v5, 0, false);
            hi = (uint)__builtin_amdgcn_cvt_pk_fp8_f32(v6, v7, (int)hi, true);
            uint2 r; r.x = lo; r.y = hi;
            *(uint2*)((char*)outp + ((size_t)node << 7) + clo) = r;
        } else {
            float v0 = diS * (a01.x + s01.x);
            float v1 = diS * (a01.y + s01.y);
            float v2 = diS * (a23.x + s23.x);
            float v3 = diS * (a23.y + s23.y);
            float v4 = diS * (a45.x + s45.x);
            float v5 = diS * (a45.y + s45.y);
            float v6 = diS * (a67.x + s67.x);
            float v7 = diS * (a67.y + s67.y);
            uint4 r;
            r.x = (uint)f2bf(v0) | ((uint)f2bf(v1) << 16);
            r.y = (uint)f2bf(v2) | ((uint)f2bf(v3) << 16);
            r.z = (uint)f2bf(v4) | ((uint)f2bf(v5) << 16);
            r.w = (uint)f2bf(v6) | ((uint)f2bf(v7) << 16);
            ((uint4*)outp)[(size_t)node * 16 + cl] = r;
        }
    }
}

// single-node fallback (fast or heavy path), used when pairing not possible
template <int MODE>
__device__ __forceinline__ void agg_node(int node, int beg, int end,
                                         int lane, int q, int cl,
                                         const char* __restrict__ xwb, uint clo,
                                         const int* __restrict__ ewsrc,
                                         const float* __restrict__ dinv,
                                         const float* __restrict__ bias,
                                         void* __restrict__ outp) {
    f32x2 a01 = {0.f, 0.f}, a23 = {0.f, 0.f}, a45 = {0.f, 0.f}, a67 = {0.f, 0.f};
    int d8 = end - beg;
    if (d8 <= 32) {
        int sv = ewsrc[beg + (lane & 31)];
        int ng = d8 >> 3;
        uint2 A0, A1, B0, B1, C0, C1, D0, D1;
        if (ng > 0) { int s0 = __shfl(sv, q),      s1 = __shfl(sv, 4 + q);  A0 = LDG2(s0); A1 = LDG2(s1); }
        if (ng > 1) { int s0 = __shfl(sv, 8 + q),  s1 = __shfl(sv, 12 + q); B0 = LDG2(s0); B1 = LDG2(s1); }
        if (ng > 2) { int s0 = __shfl(sv, 16 + q), s1 = __shfl(sv, 20 + q); C0 = LDG2(s0); C1 = LDG2(s1); }
        if (ng > 3) { int s0 = __shfl(sv, 24 + q), s1 = __shfl(sv, 28 + q); D0 = LDG2(s0); D1 = LDG2(s1); }
        if (ng > 0) { ACCU(A0); ACCU(A1); }
        if (ng > 1) { ACCU(B0); ACCU(B1); }
        if (ng > 2) { ACCU(C0); ACCU(C1); }
        if (ng > 3) { ACCU(D0); ACCU(D1); }
    } else {
        for (int c = beg; c < end; c += 64) {
            int sv = ewsrc[c + lane];
            int ce = c + 64 < end ? c + 64 : end;
            int ngr = (ce - c) >> 3;
            int s0 = __shfl(sv, q), s1 = __shfl(sv, 4 + q);
            uint2 A0 = LDG2(s0), A1 = LDG2(s1);
            for (int g = 1; g < ngr; ++g) {
                int t0 = __shfl(sv, g * 8 + q), t1 = __shfl(sv, g * 8 + 4 + q);
                uint2 B0 = LDG2(t0), B1 = LDG2(t1);
                ACCU(A0); ACCU(A1);
                A0 = B0; A1 = B1;
            }
            ACCU(A0); ACCU(A1);
        }
    }
    agg_finish<MODE>(a01, a23, a45, a67, node, lane, cl, xwb, clo, dinv, bias, outp);
}

template <int MODE>
__global__ __launch_bounds__(256) void agg_gather(const uchar* __restrict__ tab,
                                                  const int* __restrict__ ewsrc,
                                                  const int* __restrict__ rowptr,
                                                  const float* __restrict__ dinv,
                                                  const float* __restrict__ bias,
                                                  void* __restrict__ outp, int n) {
    int node0 = blockIdx.x * 8 + (threadIdx.x >> 6) * 2;
    if (node0 >= n) return;
    int lane = threadIdx.x & 63;
    int q = lane >> 4;                 // quarter 0..3: one edge each
    int cl = lane & 15;                // channels cl*8 .. cl*8+7
    const char* xwb = (const char*)tab;
    uint clo = (uint)cl << 3;
    int node1 = node0 + 1;
    bool has1 = node1 < n;
    int beg0 = rowptr[node0], end0 = rowptr[node0 + 1];   // beg1 == end0 (contiguous)
    int end1 = has1 ? rowptr[node1 + 1] : end0;
    int d80 = end0 - beg0;
    int d81 = end1 - end0;

    if (has1 && d80 <= 32 && d81 <= 32) {
        // dual fast path: issue ALL gathers for both nodes before any accumulate
        int sv0 = ewsrc[beg0 + (lane & 31)];
        int sv1 = ewsrc[end0 + (lane & 31)];
        int ng0 = d80 >> 3, ng1 = d81 >> 3;
        uint2 A0, A1, B0, B1, C0, C1, D0, D1;       // node0
        uint2 E0, E1, F0, F1, G0, G1, H0, H1;       // node1
        if (ng0 > 0) { int s0 = __shfl(sv0, q),      s1 = __shfl(sv0, 4 + q);  A0 = LDG2(s0); A1 = LDG2(s1); }
        if (ng0 > 1) { int s0 = __shfl(sv0, 8 + q),  s1 = __shfl(sv0, 12 + q); B0 = LDG2(s0); B1 = LDG2(s1); }
        if (ng0 > 2) { int s0 = __shfl(sv0, 16 + q), s1 = __shfl(sv0, 20 + q); C0 = LDG2(s0); C1 = LDG2(s1); }
        if (ng0 > 3) { int s0 = __shfl(sv0, 24 + q), s1 = __shfl(sv0, 28 + q); D0 = LDG2(s0); D1 = LDG2(s1); }
        if (ng1 > 0) { int s0 = __shfl(sv1, q),      s1 = __shfl(sv1, 4 + q);  E0 = LDG2(s0); E1 = LDG2(s1); }
        if (ng1 > 1) { int s0 = __shfl(sv1, 8 + q),  s1 = __shfl(sv1, 12 + q); F0 = LDG2(s0); F1 = LDG2(s1); }
        if (ng1 > 2) { int s0 = __shfl(sv1, 16 + q), s1 = __shfl(sv1, 20 + q); G0 = LDG2(s0); G1 = LDG2(s1); }
        if (ng1 > 3) { int s0 = __shfl(sv1, 24 + q), s1 = __shfl(sv1, 28 + q); H0 = LDG2(s0); H1 = LDG2(s1); }
        f32x2 a01 = {0.f, 0.f}, a23 = {0.f, 0.f}, a45 = {0.f, 0.f}, a67 = {0.f, 0.f};
        if (ng0 > 0) { ACCU(A0); ACCU(A1); }
        if (ng0 > 1) { ACCU(B0); ACCU(B1); }
        if (ng0 > 2) { ACCU(C0); ACCU(C1); }
        if (ng0 > 3) { ACCU(D0); ACCU(D1); }
        agg_finish<MODE>(a01, a23, a45, a67, node0, lane, cl, xwb, clo, dinv, bias, outp);
        a01 = (f32x2){0.f, 0.f}; a23 = (f32x2){0.f, 0.f};
        a45 = (f32x2){0.f, 0.f}; a67 = (f32x2){0.f, 0.f};
        if (ng1 > 0) { ACCU(E0); ACCU(E1); }
        if (ng1 > 1) { ACCU(F0); ACCU(F1); }
        if (ng1 > 2) { ACCU(G0); ACCU(G1); }
        if (ng1 > 3) { ACCU(H0); ACCU(H1); }
        agg_finish<MODE>(a01, a23, a45, a67, node1, lane, cl, xwb, clo, dinv, bias, outp);
    } else {
        agg_node<MODE>(node0, beg0, end0, lane, q, cl, xwb, clo, ewsrc, dinv, bias, outp);
        if (has1)
            agg_node<MODE>(node1, end0, end1, lane, q, cl, xwb, clo, ewsrc, dinv, bias, outp);
    }
}

// ---------------- head ----------------
__global__ __launch_bounds__(128) void final_kernel(const float* __restrict__ gsum,
                                                    const float* __restrict__ gcnt,
                                                    const float* __restrict__ Wlin,
                                                    const float* __restrict__ blin,
                                                    float* __restrict__ out) {
    __shared__ float pooled[128];
    int g = blockIdx.x;
    int c = threadIdx.x;
    float cntv = gcnt[g]; if (cntv < 1.f) cntv = 1.f;
    pooled[c] = gsum[g * 128 + c] / cntv;
    __syncthreads();
    if (c < 10) {
        float acc = blin[c];
        for (int k = 0; k < 128; ++k) acc += pooled[k] * Wlin[k * 10 + c];
        out[g * 10 + c] = acc;
    }
}

extern "C" void kernel_launch(void* const* d_in, const int* in_sizes, int n_in,
                              void* d_out, int out_size, void* d_ws, size_t ws_size,
                              hipStream_t stream) {
    const float* x    = (const float*)d_in[0];
    const int*   ei   = (const int*)d_in[1];
    const int*   batch= (const int*)d_in[2];
    const float* W1   = (const float*)d_in[3];
    const float* b1   = (const float*)d_in[4];
    const float* W2   = (const float*)d_in[5];
    const float* b2   = (const float*)d_in[6];
    const float* Wlin = (const float*)d_in[7];
    const float* blin = (const float*)d_in[8];
    float* out = (float*)d_out;

    const int n = in_sizes[0] / 128;
    const int e = in_sizes[1] / 2;
    const int* src = ei;
    const int* dst = ei + e;
    const int nb_bkt = (n + R_NODES - 1) >> R_LOG;

    char* ws = (char*)d_ws;
    size_t off = 0;
    auto take = [&](size_t bytes) -> char* {
        char* p = ws + off;
        off = (off + bytes + 255) & ~(size_t)255;
        return p;
    };
    int*    rowptr = (int*)   take((size_t)(n + 1) * 4);
    int*    cnt    = (int*)   take((size_t)n * 4);
    float*  dinv   = (float*) take((size_t)n * 4);
    int*    bktsum = (int*)   take((size_t)NB_MAX * 4);
    int*    ewsrc  = (int*)   take(((size_t)e + 7ull * (size_t)n + 64) * 4);  // padded CSR
    uchar*  T1     = (uchar*) take((size_t)(n + 1) * 128);   // fp8 table L1 (+pad row)
    uchar*  T2     = (uchar*) take((size_t)(n + 1) * 128);   // fp8 table L2 (+pad row)
    ushort* V      = (ushort*)take((size_t)n * 128 * 2);     // bf16 v' (GEMM2 input)
    // zero-init block: gbcur | gsum | gcnt — contiguous, one memset
    int*    gbcur  = (int*)   take((size_t)NB_MAX * 4);
    float*  gsum   = (float*) take(64 * 128 * 4);
    float*  gcnt   = (float*) take(64 * 4);
    (void)ws_size;
    int* buck = (int*)V;    // alias: 12.8MB <= 25.6MB; consumed before agg2 writes V

    size_t zspan = (size_t)((char*)gcnt + 64 * 4 - (char*)gbcur);
    hipMemsetAsync(gbcur, 0, zspan, stream);

    bin_pass<<<(e + CH - 1) / CH, 1024, 0, stream>>>(src, dst, e, gbcur, buck, nb_bkt);
    count_pass<<<nb_bkt, 256, 0, stream>>>(buck, gbcur, cnt, dinv, bktsum,
                                           (uint*)(T1 + (size_t)n * 128),
                                           (uint*)(T2 + (size_t)n * 128), n);

    const int ntiles = (n + 255) / 256;
    const int ngem = (ntiles + 1) / 2;
    csr_gemm1<<<ngem + nb_bkt, 512, 0, stream>>>(buck, cnt, bktsum, gbcur, n, nb_bkt,
                                                 ngem, ntiles, ewsrc, rowptr,
                                                 x, W1, dinv, T1);

    // layer 1 aggregate: T2 = fp8(FS*dinv*relu(dinv*(sum+self)/FS + b1))
    agg_gather<0><<<(n + 7) / 8, 256, 0, stream>>>(T1, ewsrc, rowptr, dinv, b1, T2, n);
    // layer 2 aggregate (commuted): v' = dinv*(sum+self)/FS, bf16
    agg_gather<1><<<(n + 7) / 8, 256, 0, stream>>>(T2, ewsrc, rowptr, dinv, b1, V, n);
    // layer 2 GEMM + relu + mean-pool (writes only pooled atomics)
    gemm2_pool<<<ngem, 512, 0, stream>>>(V, W2, b2, batch, gsum, gcnt, n, ntiles);

    final_kernel<<<64, 128, 0, stream>>>(gsum, gcnt, Wlin, blin, out);
}